// Round 1
// baseline (663.931 us; speedup 1.0000x reference)
//
#include <hip/hip_runtime.h>

#define N_NODES 10000
#define N_EDGES 320000
#define DIM_IN  256
#define DD      128
#define HH      4
#define HD      512
#define GG      64

// ---------------- CSR build ----------------
__global__ void hist_kernel(const int* __restrict__ dst, int* __restrict__ cnt) {
  int e = blockIdx.x * 256 + threadIdx.x;
  atomicAdd(&cnt[dst[e]], 1);
}

__global__ void scan_kernel(const int* __restrict__ cnt, int* __restrict__ row_off) {
  __shared__ int part[1024];
  int t = threadIdx.x;
  int base = t * 10;
  int s = 0;
#pragma unroll
  for (int i = 0; i < 10; i++) { int idx = base + i; if (idx < N_NODES) s += cnt[idx]; }
  part[t] = s;
  __syncthreads();
  for (int off = 1; off < 1024; off <<= 1) {
    int v = (t >= off) ? part[t - off] : 0;
    __syncthreads();
    part[t] += v;
    __syncthreads();
  }
  int run = part[t] - s;  // exclusive base for this thread's chunk
  for (int i = 0; i < 10; i++) {
    int idx = base + i;
    if (idx < N_NODES) { row_off[idx] = run; run += cnt[idx]; }
  }
  if (t == 1023) row_off[N_NODES] = part[1023];
}

__global__ void scatter_kernel(const int* __restrict__ dst, const int* __restrict__ row_off,
                               int* __restrict__ fill, int* __restrict__ elist) {
  int e = blockIdx.x * 256 + threadIdx.x;
  int d = dst[e];
  int pos = row_off[d] + atomicAdd(&fill[d], 1);
  elist[pos] = e;
}

// ---------------- dual GEMM: C1 = A@B1+bias1, C2 = A@B2+bias2 ----------------
template <int K, int NCOL>
__global__ __launch_bounds__(256) void dual_gemm(
    const float* __restrict__ A,
    const float* __restrict__ B1, const float* __restrict__ bias1,
    const float* __restrict__ B2, const float* __restrict__ bias2,
    float* __restrict__ C1, float* __restrict__ C2, int M) {
  __shared__ float As[64][17];
  __shared__ float Bs[16][65];
  __shared__ float Bd[16][65];
  int t = threadIdx.x;
  int col0 = blockIdx.x * 64;
  int row0 = blockIdx.y * 64;
  int ar = t >> 2, ac = (t & 3) * 4;
  int bk = t >> 4, bc = (t & 15) * 4;
  int tx = t & 15, ty = t >> 4;
  float acc1[4][4] = {}, acc2[4][4] = {};
  for (int k0 = 0; k0 < K; k0 += 16) {
    float4 av = make_float4(0.f, 0.f, 0.f, 0.f);
    if (row0 + ar < M) av = *(const float4*)(A + (size_t)(row0 + ar) * K + k0 + ac);
    float4 b1v = *(const float4*)(B1 + (size_t)(k0 + bk) * NCOL + col0 + bc);
    float4 b2v = *(const float4*)(B2 + (size_t)(k0 + bk) * NCOL + col0 + bc);
    __syncthreads();
    As[ar][ac] = av.x; As[ar][ac + 1] = av.y; As[ar][ac + 2] = av.z; As[ar][ac + 3] = av.w;
    Bs[bk][bc] = b1v.x; Bs[bk][bc + 1] = b1v.y; Bs[bk][bc + 2] = b1v.z; Bs[bk][bc + 3] = b1v.w;
    Bd[bk][bc] = b2v.x; Bd[bk][bc + 1] = b2v.y; Bd[bk][bc + 2] = b2v.z; Bd[bk][bc + 3] = b2v.w;
    __syncthreads();
#pragma unroll
    for (int kk = 0; kk < 16; kk++) {
      float a[4], br1r[4], br2r[4];
#pragma unroll
      for (int i = 0; i < 4; i++) a[i] = As[ty * 4 + i][kk];
#pragma unroll
      for (int j = 0; j < 4; j++) { br1r[j] = Bs[kk][tx * 4 + j]; br2r[j] = Bd[kk][tx * 4 + j]; }
#pragma unroll
      for (int i = 0; i < 4; i++)
#pragma unroll
        for (int j = 0; j < 4; j++) {
          acc1[i][j] = fmaf(a[i], br1r[j], acc1[i][j]);
          acc2[i][j] = fmaf(a[i], br2r[j], acc2[i][j]);
        }
    }
  }
#pragma unroll
  for (int i = 0; i < 4; i++) {
    int row = row0 + ty * 4 + i;
    if (row < M) {
      float4 o1, o2;
      int cb = col0 + tx * 4;
      o1.x = acc1[i][0] + bias1[cb + 0]; o1.y = acc1[i][1] + bias1[cb + 1];
      o1.z = acc1[i][2] + bias1[cb + 2]; o1.w = acc1[i][3] + bias1[cb + 3];
      o2.x = acc2[i][0] + bias2[cb + 0]; o2.y = acc2[i][1] + bias2[cb + 1];
      o2.z = acc2[i][2] + bias2[cb + 2]; o2.w = acc2[i][3] + bias2[cb + 3];
      *(float4*)(C1 + (size_t)row * NCOL + cb) = o1;
      *(float4*)(C2 + (size_t)row * NCOL + cb) = o2;
    }
  }
}

// ---------------- layer 1 edge scores (H=4, D=128) ----------------
__global__ __launch_bounds__(256) void edge_score1(
    const float* __restrict__ hs, const float* __restrict__ hd,
    const float* __restrict__ attn, const int* __restrict__ src,
    const int* __restrict__ dst, float* __restrict__ sc) {
  __shared__ float a_lds[512];
  int t = threadIdx.x;
  a_lds[t] = attn[t];
  a_lds[t + 256] = attn[t + 256];
  __syncthreads();
  int e = blockIdx.x * 4 + (t >> 6);
  int lane = t & 63;
  int s = src[e], d = dst[e];
  const float* ps = hs + (size_t)s * HD + lane * 8;
  const float* pd = hd + (size_t)d * HD + lane * 8;
  float4 s0 = *(const float4*)ps, s1 = *(const float4*)(ps + 4);
  float4 d0 = *(const float4*)pd, d1 = *(const float4*)(pd + 4);
  const float* av = a_lds + lane * 8;
  float p = 0.f, v;
  v = s0.x + d0.x; v = v > 0.f ? v : 0.2f * v; p = fmaf(v, av[0], p);
  v = s0.y + d0.y; v = v > 0.f ? v : 0.2f * v; p = fmaf(v, av[1], p);
  v = s0.z + d0.z; v = v > 0.f ? v : 0.2f * v; p = fmaf(v, av[2], p);
  v = s0.w + d0.w; v = v > 0.f ? v : 0.2f * v; p = fmaf(v, av[3], p);
  v = s1.x + d1.x; v = v > 0.f ? v : 0.2f * v; p = fmaf(v, av[4], p);
  v = s1.y + d1.y; v = v > 0.f ? v : 0.2f * v; p = fmaf(v, av[5], p);
  v = s1.z + d1.z; v = v > 0.f ? v : 0.2f * v; p = fmaf(v, av[6], p);
  v = s1.w + d1.w; v = v > 0.f ? v : 0.2f * v; p = fmaf(v, av[7], p);
#pragma unroll
  for (int k = 1; k < 16; k <<= 1) p += __shfl_xor(p, k);
  if ((lane & 15) == 0) sc[(size_t)e * 4 + (lane >> 4)] = p;
}

// ---------------- layer 1 per-node softmax + aggregation ----------------
__global__ __launch_bounds__(256) void node_agg1(
    const float* __restrict__ hs, const int* __restrict__ src,
    const float* __restrict__ sc, const int* __restrict__ row_off,
    const int* __restrict__ elist, float* __restrict__ out) {
  int v = blockIdx.x;
  int start = row_off[v];
  int deg = row_off[v + 1] - start;
  int t = threadIdx.x;
  __shared__ float m_sh[4], rd_sh[4];
  __shared__ float alpha[64][4];
  __shared__ int s_lds[64];
  int w = t >> 6, lane = t & 63;
  float mx = -1e30f;
  for (int i = lane; i < deg; i += 64) mx = fmaxf(mx, sc[(size_t)elist[start + i] * 4 + w]);
#pragma unroll
  for (int k = 1; k < 64; k <<= 1) mx = fmaxf(mx, __shfl_xor(mx, k));
  float sm = 0.f;
  for (int i = lane; i < deg; i += 64) sm += __expf(sc[(size_t)elist[start + i] * 4 + w] - mx);
#pragma unroll
  for (int k = 1; k < 64; k <<= 1) sm += __shfl_xor(sm, k);
  if (lane == 0) { m_sh[w] = mx; rd_sh[w] = sm > 0.f ? 1.f / sm : 0.f; }
  int slot0 = t, slot1 = t + 256;
  int h0 = t >> 7, h1 = 2 + (t >> 7);
  float acc0 = 0.f, acc1 = 0.f;
  for (int c0 = 0; c0 < deg; c0 += 64) {
    int cn = min(64, deg - c0);
    __syncthreads();
    if (t < cn) {
      int e = elist[start + c0 + t];
      s_lds[t] = src[e];
      float4 srow = *(const float4*)(sc + (size_t)e * 4);
      alpha[t][0] = __expf(srow.x - m_sh[0]) * rd_sh[0];
      alpha[t][1] = __expf(srow.y - m_sh[1]) * rd_sh[1];
      alpha[t][2] = __expf(srow.z - m_sh[2]) * rd_sh[2];
      alpha[t][3] = __expf(srow.w - m_sh[3]) * rd_sh[3];
    }
    __syncthreads();
    for (int i = 0; i < cn; i++) {
      const float* row = hs + (size_t)s_lds[i] * HD;
      acc0 = fmaf(alpha[i][h0], row[slot0], acc0);
      acc1 = fmaf(alpha[i][h1], row[slot1], acc1);
    }
  }
  out[(size_t)v * HD + slot0] = acc0;
  out[(size_t)v * HD + slot1] = acc1;
}

// ---------------- layer 2 edge scores (H=1, D=128) ----------------
__global__ __launch_bounds__(256) void edge_score2(
    const float* __restrict__ hs, const float* __restrict__ hd,
    const float* __restrict__ attn, const int* __restrict__ src,
    const int* __restrict__ dst, float* __restrict__ sc) {
  __shared__ float a_lds[128];
  int t = threadIdx.x;
  if (t < 128) a_lds[t] = attn[t];
  __syncthreads();
  int e = blockIdx.x * 4 + (t >> 6);
  int lane = t & 63;
  int s = src[e], d = dst[e];
  float2 sv = *(const float2*)(hs + (size_t)s * DD + lane * 2);
  float2 dv = *(const float2*)(hd + (size_t)d * DD + lane * 2);
  float v0 = sv.x + dv.x; v0 = v0 > 0.f ? v0 : 0.2f * v0;
  float v1 = sv.y + dv.y; v1 = v1 > 0.f ? v1 : 0.2f * v1;
  float p = v0 * a_lds[lane * 2] + v1 * a_lds[lane * 2 + 1];
#pragma unroll
  for (int k = 1; k < 64; k <<= 1) p += __shfl_xor(p, k);
  if (lane == 0) sc[e] = p;
}

// ---------------- layer 2 per-node softmax + aggregation ----------------
__global__ __launch_bounds__(64) void node_agg2(
    const float* __restrict__ hs, const int* __restrict__ src,
    const float* __restrict__ sc, const int* __restrict__ row_off,
    const int* __restrict__ elist, float* __restrict__ out) {
  int v = blockIdx.x;
  int start = row_off[v];
  int deg = row_off[v + 1] - start;
  int lane = threadIdx.x;
  float mx = -1e30f;
  for (int i = lane; i < deg; i += 64) mx = fmaxf(mx, sc[elist[start + i]]);
#pragma unroll
  for (int k = 1; k < 64; k <<= 1) mx = fmaxf(mx, __shfl_xor(mx, k));
  float sm = 0.f;
  for (int i = lane; i < deg; i += 64) sm += __expf(sc[elist[start + i]] - mx);
#pragma unroll
  for (int k = 1; k < 64; k <<= 1) sm += __shfl_xor(sm, k);
  float rd = sm > 0.f ? 1.f / sm : 0.f;
  __shared__ float al[64];
  __shared__ int sl[64];
  float acc0 = 0.f, acc1 = 0.f;
  for (int c0 = 0; c0 < deg; c0 += 64) {
    int cn = min(64, deg - c0);
    __syncthreads();
    if (lane < cn) {
      int e = elist[start + c0 + lane];
      sl[lane] = src[e];
      al[lane] = __expf(sc[e] - mx) * rd;
    }
    __syncthreads();
    for (int i = 0; i < cn; i++) {
      const float* row = hs + (size_t)sl[i] * DD;
      acc0 = fmaf(al[i], row[lane], acc0);
      acc1 = fmaf(al[i], row[lane + 64], acc1);
    }
  }
  out[(size_t)v * DD + lane] = acc0;
  out[(size_t)v * DD + lane + 64] = acc1;
}

// ---------------- graph mean pool ----------------
__global__ __launch_bounds__(128) void pool_kernel(
    const float* __restrict__ h2, const int* __restrict__ gid,
    float* __restrict__ hg, float* __restrict__ cntg) {
  int v = blockIdx.x;
  int t = threadIdx.x;
  int g = gid[v];
  atomicAdd(&hg[g * DD + t], h2[(size_t)v * DD + t]);
  if (t == 0) atomicAdd(&cntg[g], 1.0f);
}

// ---------------- readout MLP ----------------
__global__ __launch_bounds__(64) void final_kernel(
    const float* __restrict__ hg, const float* __restrict__ cntg,
    const float* __restrict__ Wr1, const float* __restrict__ br1,
    const float* __restrict__ Wr2, const float* __restrict__ br2,
    float* __restrict__ out) {
  int g = blockIdx.x, t = threadIdx.x;
  __shared__ float hgn[128];
  float inv = 1.f / fmaxf(cntg[g], 1.f);
  hgn[t] = hg[g * DD + t] * inv;
  hgn[t + 64] = hg[g * DD + t + 64] * inv;
  __syncthreads();
  float r = br1[t];
#pragma unroll 8
  for (int k = 0; k < 128; k++) r = fmaf(hgn[k], Wr1[k * 64 + t], r);
  r = fmaxf(r, 0.f);
  float p = r * Wr2[t];
#pragma unroll
  for (int k = 1; k < 64; k <<= 1) p += __shfl_xor(p, k);
  if (t == 0) out[g] = p + br2[0];
}

extern "C" void kernel_launch(void* const* d_in, const int* in_sizes, int n_in,
                              void* d_out, int out_size, void* d_ws, size_t ws_size,
                              hipStream_t stream) {
  (void)in_sizes; (void)n_in; (void)out_size; (void)ws_size;
  const float* x     = (const float*)d_in[0];
  const float* W1s   = (const float*)d_in[1];
  const float* b1s   = (const float*)d_in[2];
  const float* W1d   = (const float*)d_in[3];
  const float* b1d   = (const float*)d_in[4];
  const float* attn1 = (const float*)d_in[5];
  const float* W2s   = (const float*)d_in[6];
  const float* b2s   = (const float*)d_in[7];
  const float* W2d   = (const float*)d_in[8];
  const float* b2d   = (const float*)d_in[9];
  const float* attn2 = (const float*)d_in[10];
  const float* Wr1   = (const float*)d_in[11];
  const float* br1   = (const float*)d_in[12];
  const float* Wr2   = (const float*)d_in[13];
  const float* br2   = (const float*)d_in[14];
  const int* src     = (const int*)d_in[15];
  const int* dst     = (const int*)d_in[16];
  const int* gid     = (const int*)d_in[17];
  float* out = (float*)d_out;

  char* ws = (char*)d_ws;
  float* hs1   = (float*)(ws + 0);          // N*512 f32 = 20,480,000 B
  float* hd1   = (float*)(ws + 20480000);   // N*512 f32
  float* h1    = (float*)(ws + 40960000);   // N*512 f32
  float* sc1   = (float*)(ws + 61440000);   // E*4 f32 = 5,120,000 B
  int*   elist = (int*)(ws + 66560000);     // E int = 1,280,000 B
  int*   row_off = (int*)(ws + 67840000);   // (N+1) int
  int*   cnt   = (int*)(ws + 67880448);     // N int
  int*   fill  = (int*)(ws + 67920896);     // N int
  float* hg    = (float*)(ws + 67961344);   // G*128 f32 = 32,768 B
  float* cntg  = (float*)(ws + 67994112);   // G f32
  // reuse for layer 2
  float* hs2 = hs1;
  float* hd2 = hd1;
  float* sc2 = sc1;
  float* h2  = h1;

  hipMemsetAsync(cnt, 0, N_NODES * 4, stream);
  hipMemsetAsync(fill, 0, N_NODES * 4, stream);
  hipMemsetAsync(hg, 0, (GG * DD + GG) * 4, stream);

  hist_kernel<<<N_EDGES / 256, 256, 0, stream>>>(dst, cnt);
  scan_kernel<<<1, 1024, 0, stream>>>(cnt, row_off);
  scatter_kernel<<<N_EDGES / 256, 256, 0, stream>>>(dst, row_off, fill, elist);

  dual_gemm<DIM_IN, HD><<<dim3(HD / 64, (N_NODES + 63) / 64), 256, 0, stream>>>(
      x, W1s, b1s, W1d, b1d, hs1, hd1, N_NODES);
  edge_score1<<<N_EDGES / 4, 256, 0, stream>>>(hs1, hd1, attn1, src, dst, sc1);
  node_agg1<<<N_NODES, 256, 0, stream>>>(hs1, src, sc1, row_off, elist, h1);

  dual_gemm<HD, DD><<<dim3(DD / 64, (N_NODES + 63) / 64), 256, 0, stream>>>(
      h1, W2s, b2s, W2d, b2d, hs2, hd2, N_NODES);
  edge_score2<<<N_EDGES / 4, 256, 0, stream>>>(hs2, hd2, attn2, src, dst, sc2);
  node_agg2<<<N_NODES, 64, 0, stream>>>(hs2, src, sc2, row_off, elist, h2);

  pool_kernel<<<N_NODES, 128, 0, stream>>>(h2, gid, hg, cntg);
  final_kernel<<<GG, 64, 0, stream>>>(hg, cntg, Wr1, br1, Wr2, br2, out);
}

// Round 2
// 390.741 us; speedup vs baseline: 1.6992x; 1.6992x over previous
//
#include <hip/hip_runtime.h>

#define N_NODES 10000
#define N_EDGES 320000
#define DIM_IN  256
#define DD      128
#define HH      4
#define HD      512
#define GG      64

// ---------------- CSR build ----------------
__global__ void hist_kernel(const int* __restrict__ dst, int* __restrict__ cnt) {
  int e = blockIdx.x * 256 + threadIdx.x;
  atomicAdd(&cnt[dst[e]], 1);
}

__global__ void scan_kernel(const int* __restrict__ cnt, int* __restrict__ row_off) {
  __shared__ int part[1024];
  int t = threadIdx.x;
  int base = t * 10;
  int s = 0;
#pragma unroll
  for (int i = 0; i < 10; i++) { int idx = base + i; if (idx < N_NODES) s += cnt[idx]; }
  part[t] = s;
  __syncthreads();
  for (int off = 1; off < 1024; off <<= 1) {
    int v = (t >= off) ? part[t - off] : 0;
    __syncthreads();
    part[t] += v;
    __syncthreads();
  }
  int run = part[t] - s;  // exclusive base for this thread's chunk
  for (int i = 0; i < 10; i++) {
    int idx = base + i;
    if (idx < N_NODES) { row_off[idx] = run; run += cnt[idx]; }
  }
  if (t == 1023) row_off[N_NODES] = part[1023];
}

// store src node id directly (saves a dependent load in the fused kernels)
__global__ void scatter_kernel(const int* __restrict__ src, const int* __restrict__ dst,
                               const int* __restrict__ row_off,
                               int* __restrict__ fill, int* __restrict__ srcl) {
  int e = blockIdx.x * 256 + threadIdx.x;
  int d = dst[e];
  int pos = row_off[d] + atomicAdd(&fill[d], 1);
  srcl[pos] = src[e];
}

// ---------------- dual GEMM: C1 = A@B1+bias1, C2 = A@B2+bias2 ----------------
template <int K, int NCOL>
__global__ __launch_bounds__(256) void dual_gemm(
    const float* __restrict__ A,
    const float* __restrict__ B1, const float* __restrict__ bias1,
    const float* __restrict__ B2, const float* __restrict__ bias2,
    float* __restrict__ C1, float* __restrict__ C2, int M) {
  __shared__ float As[64][68];
  __shared__ float Bs[16][68];
  __shared__ float Bd[16][68];
  int t = threadIdx.x;
  int col0 = blockIdx.x * 64;
  int row0 = blockIdx.y * 64;
  int ar = t >> 2, ac = (t & 3) * 4;
  int bk = t >> 4, bc = (t & 15) * 4;
  int tx = t & 15, ty = t >> 4;
  float acc1[4][4] = {}, acc2[4][4] = {};
  for (int k0 = 0; k0 < K; k0 += 16) {
    float4 av = make_float4(0.f, 0.f, 0.f, 0.f);
    if (row0 + ar < M) av = *(const float4*)(A + (size_t)(row0 + ar) * K + k0 + ac);
    float4 b1v = *(const float4*)(B1 + (size_t)(k0 + bk) * NCOL + col0 + bc);
    float4 b2v = *(const float4*)(B2 + (size_t)(k0 + bk) * NCOL + col0 + bc);
    __syncthreads();
    *(float4*)&As[ar][ac] = av;
    *(float4*)&Bs[bk][bc] = b1v;
    *(float4*)&Bd[bk][bc] = b2v;
    __syncthreads();
#pragma unroll
    for (int kk = 0; kk < 16; kk++) {
      float a[4];
#pragma unroll
      for (int i = 0; i < 4; i++) a[i] = As[ty * 4 + i][kk];
      float4 br1 = *(const float4*)&Bs[kk][tx * 4];
      float4 br2 = *(const float4*)&Bd[kk][tx * 4];
      float b1r[4] = {br1.x, br1.y, br1.z, br1.w};
      float b2r[4] = {br2.x, br2.y, br2.z, br2.w};
#pragma unroll
      for (int i = 0; i < 4; i++)
#pragma unroll
        for (int j = 0; j < 4; j++) {
          acc1[i][j] = fmaf(a[i], b1r[j], acc1[i][j]);
          acc2[i][j] = fmaf(a[i], b2r[j], acc2[i][j]);
        }
    }
  }
#pragma unroll
  for (int i = 0; i < 4; i++) {
    int row = row0 + ty * 4 + i;
    if (row < M) {
      float4 o1, o2;
      int cb = col0 + tx * 4;
      o1.x = acc1[i][0] + bias1[cb + 0]; o1.y = acc1[i][1] + bias1[cb + 1];
      o1.z = acc1[i][2] + bias1[cb + 2]; o1.w = acc1[i][3] + bias1[cb + 3];
      o2.x = acc2[i][0] + bias2[cb + 0]; o2.y = acc2[i][1] + bias2[cb + 1];
      o2.z = acc2[i][2] + bias2[cb + 2]; o2.w = acc2[i][3] + bias2[cb + 3];
      *(float4*)(C1 + (size_t)row * NCOL + cb) = o1;
      *(float4*)(C2 + (size_t)row * NCOL + cb) = o2;
    }
  }
}

// ---------------- layer 1 fused: scores + online softmax + aggregation ----------------
// block = node, 4 waves; each wave owns edges i = w, w+4, ...
// lane covers 8 slots (head = slot>>7); score reduced within 16-lane head groups.
__global__ __launch_bounds__(256) void fused_gat1(
    const float* __restrict__ hs, const float* __restrict__ hd,
    const float* __restrict__ attn, const int* __restrict__ row_off,
    const int* __restrict__ srcl, float* __restrict__ out) {
  int v = blockIdx.x;
  int t = threadIdx.x;
  int w = t >> 6, lane = t & 63;
  int start = row_off[v];
  int deg = row_off[v + 1] - start;

  const float* ap = attn + lane * 8;
  const float* hp = hd + (size_t)v * HD + lane * 8;
  float4 a0 = *(const float4*)ap, a1 = *(const float4*)(ap + 4);
  float4 g0 = *(const float4*)hp, g1 = *(const float4*)(hp + 4);
  float areg[8] = {a0.x, a0.y, a0.z, a0.w, a1.x, a1.y, a1.z, a1.w};
  float hdreg[8] = {g0.x, g0.y, g0.z, g0.w, g1.x, g1.y, g1.z, g1.w};

  float m = -3.0e38f, ssum = 0.f;
  float acc[8] = {0.f, 0.f, 0.f, 0.f, 0.f, 0.f, 0.f, 0.f};

  int i = w;
  float4 c0, c1;
  if (i < deg) {
    const float* p = hs + (size_t)srcl[start + i] * HD + lane * 8;
    c0 = *(const float4*)p;
    c1 = *(const float4*)(p + 4);
  }
  while (i < deg) {
    float4 u0 = c0, u1 = c1;
    int inx = i + 4;
    if (inx < deg) {
      const float* p = hs + (size_t)srcl[start + inx] * HD + lane * 8;
      c0 = *(const float4*)p;
      c1 = *(const float4*)(p + 4);
    }
    float hv[8] = {u0.x, u0.y, u0.z, u0.w, u1.x, u1.y, u1.z, u1.w};
    float part = 0.f;
#pragma unroll
    for (int j = 0; j < 8; j++) {
      float val = hv[j] + hdreg[j];
      val = val > 0.f ? val : 0.2f * val;
      part = fmaf(val, areg[j], part);
    }
#pragma unroll
    for (int k = 1; k < 16; k <<= 1) part += __shfl_xor(part, k);
    float mn = fmaxf(m, part);
    float sc = __expf(m - mn);
    float wg = __expf(part - mn);
    ssum = fmaf(ssum, sc, wg);
#pragma unroll
    for (int j = 0; j < 8; j++) acc[j] = fmaf(acc[j], sc, wg * hv[j]);
    m = mn;
    i = inx;
  }

  __shared__ float accS[4][512];
  __shared__ float mS[4][4], sS[4][4];
  *(float4*)&accS[w][lane * 8] = make_float4(acc[0], acc[1], acc[2], acc[3]);
  *(float4*)&accS[w][lane * 8 + 4] = make_float4(acc[4], acc[5], acc[6], acc[7]);
  if ((lane & 15) == 0) { mS[w][lane >> 4] = m; sS[w][lane >> 4] = ssum; }
  __syncthreads();
#pragma unroll
  for (int rep = 0; rep < 2; rep++) {
    int slot = t + rep * 256;
    int h = slot >> 7;
    float M = fmaxf(fmaxf(mS[0][h], mS[1][h]), fmaxf(mS[2][h], mS[3][h]));
    float denom = 0.f, num = 0.f;
#pragma unroll
    for (int ww = 0; ww < 4; ww++) {
      float f = __expf(mS[ww][h] - M);
      denom = fmaf(sS[ww][h], f, denom);
      num = fmaf(accS[ww][slot], f, num);
    }
    out[(size_t)v * HD + slot] = denom > 0.f ? num / denom : 0.f;
  }
}

// ---------------- layer 2 fused (H=1, D=128) ----------------
__global__ __launch_bounds__(256) void fused_gat2(
    const float* __restrict__ hs, const float* __restrict__ hd,
    const float* __restrict__ attn, const int* __restrict__ row_off,
    const int* __restrict__ srcl, float* __restrict__ out) {
  int v = blockIdx.x;
  int t = threadIdx.x;
  int w = t >> 6, lane = t & 63;
  int start = row_off[v];
  int deg = row_off[v + 1] - start;

  float2 a = *(const float2*)(attn + lane * 2);
  float2 hdv = *(const float2*)(hd + (size_t)v * DD + lane * 2);

  float m = -3.0e38f, ssum = 0.f, acc0 = 0.f, acc1 = 0.f;
  int i = w;
  float2 c;
  if (i < deg) c = *(const float2*)(hs + (size_t)srcl[start + i] * DD + lane * 2);
  while (i < deg) {
    float2 u = c;
    int inx = i + 4;
    if (inx < deg) c = *(const float2*)(hs + (size_t)srcl[start + inx] * DD + lane * 2);
    float v0 = u.x + hdv.x; v0 = v0 > 0.f ? v0 : 0.2f * v0;
    float v1 = u.y + hdv.y; v1 = v1 > 0.f ? v1 : 0.2f * v1;
    float part = fmaf(v0, a.x, v1 * a.y);
#pragma unroll
    for (int k = 1; k < 64; k <<= 1) part += __shfl_xor(part, k);
    float mn = fmaxf(m, part);
    float sc = __expf(m - mn);
    float wg = __expf(part - mn);
    ssum = fmaf(ssum, sc, wg);
    acc0 = fmaf(acc0, sc, wg * u.x);
    acc1 = fmaf(acc1, sc, wg * u.y);
    m = mn;
    i = inx;
  }

  __shared__ float accS[4][128];
  __shared__ float mS[4], sS[4];
  accS[w][lane * 2] = acc0;
  accS[w][lane * 2 + 1] = acc1;
  if (lane == 0) { mS[w] = m; sS[w] = ssum; }
  __syncthreads();
  if (t < DD) {
    float M = fmaxf(fmaxf(mS[0], mS[1]), fmaxf(mS[2], mS[3]));
    float denom = 0.f, num = 0.f;
#pragma unroll
    for (int ww = 0; ww < 4; ww++) {
      float f = __expf(mS[ww] - M);
      denom = fmaf(sS[ww], f, denom);
      num = fmaf(accS[ww][t], f, num);
    }
    out[(size_t)v * DD + t] = denom > 0.f ? num / denom : 0.f;
  }
}

// ---------------- graph mean pool ----------------
__global__ __launch_bounds__(128) void pool_kernel(
    const float* __restrict__ h2, const int* __restrict__ gid,
    float* __restrict__ hg, float* __restrict__ cntg) {
  int v = blockIdx.x;
  int t = threadIdx.x;
  int g = gid[v];
  atomicAdd(&hg[g * DD + t], h2[(size_t)v * DD + t]);
  if (t == 0) atomicAdd(&cntg[g], 1.0f);
}

// ---------------- readout MLP ----------------
__global__ __launch_bounds__(64) void final_kernel(
    const float* __restrict__ hg, const float* __restrict__ cntg,
    const float* __restrict__ Wr1, const float* __restrict__ br1,
    const float* __restrict__ Wr2, const float* __restrict__ br2,
    float* __restrict__ out) {
  int g = blockIdx.x, t = threadIdx.x;
  __shared__ float hgn[128];
  float inv = 1.f / fmaxf(cntg[g], 1.f);
  hgn[t] = hg[g * DD + t] * inv;
  hgn[t + 64] = hg[g * DD + t + 64] * inv;
  __syncthreads();
  float r = br1[t];
#pragma unroll 8
  for (int k = 0; k < 128; k++) r = fmaf(hgn[k], Wr1[k * 64 + t], r);
  r = fmaxf(r, 0.f);
  float p = r * Wr2[t];
#pragma unroll
  for (int k = 1; k < 64; k <<= 1) p += __shfl_xor(p, k);
  if (t == 0) out[g] = p + br2[0];
}

extern "C" void kernel_launch(void* const* d_in, const int* in_sizes, int n_in,
                              void* d_out, int out_size, void* d_ws, size_t ws_size,
                              hipStream_t stream) {
  (void)in_sizes; (void)n_in; (void)out_size; (void)ws_size;
  const float* x     = (const float*)d_in[0];
  const float* W1s   = (const float*)d_in[1];
  const float* b1s   = (const float*)d_in[2];
  const float* W1d   = (const float*)d_in[3];
  const float* b1d   = (const float*)d_in[4];
  const float* attn1 = (const float*)d_in[5];
  const float* W2s   = (const float*)d_in[6];
  const float* b2s   = (const float*)d_in[7];
  const float* W2d   = (const float*)d_in[8];
  const float* b2d   = (const float*)d_in[9];
  const float* attn2 = (const float*)d_in[10];
  const float* Wr1   = (const float*)d_in[11];
  const float* br1   = (const float*)d_in[12];
  const float* Wr2   = (const float*)d_in[13];
  const float* br2   = (const float*)d_in[14];
  const int* src     = (const int*)d_in[15];
  const int* dst     = (const int*)d_in[16];
  const int* gid     = (const int*)d_in[17];
  float* out = (float*)d_out;

  char* ws = (char*)d_ws;
  float* hs1     = (float*)(ws + 0);          // N*512 f32 = 20,480,000 B
  float* hd1     = (float*)(ws + 20480000);   // N*512 f32
  float* h1      = (float*)(ws + 40960000);   // N*512 f32
  int*   srcl    = (int*)(ws + 61440000);     // E int = 1,280,000 B
  int*   row_off = (int*)(ws + 62720000);     // (N+1) int
  int*   cnt     = (int*)(ws + 62760448);     // N int
  int*   fill    = (int*)(ws + 62800896);     // N int
  float* hg      = (float*)(ws + 62841344);   // G*128 f32
  float* cntg    = (float*)(ws + 62874112);   // G f32
  // layer-2 reuse
  float* hs2 = hs1;
  float* hd2 = hd1;
  float* h2  = h1;

  hipMemsetAsync(cnt, 0, N_NODES * 4, stream);
  hipMemsetAsync(fill, 0, N_NODES * 4, stream);
  hipMemsetAsync(hg, 0, (GG * DD + GG) * 4, stream);

  hist_kernel<<<N_EDGES / 256, 256, 0, stream>>>(dst, cnt);
  scan_kernel<<<1, 1024, 0, stream>>>(cnt, row_off);
  scatter_kernel<<<N_EDGES / 256, 256, 0, stream>>>(src, dst, row_off, fill, srcl);

  dual_gemm<DIM_IN, HD><<<dim3(HD / 64, (N_NODES + 63) / 64), 256, 0, stream>>>(
      x, W1s, b1s, W1d, b1d, hs1, hd1, N_NODES);
  fused_gat1<<<N_NODES, 256, 0, stream>>>(hs1, hd1, attn1, row_off, srcl, h1);

  dual_gemm<HD, DD><<<dim3(DD / 64, (N_NODES + 63) / 64), 256, 0, stream>>>(
      h1, W2s, b2s, W2d, b2d, hs2, hd2, N_NODES);
  fused_gat2<<<N_NODES, 256, 0, stream>>>(hs2, hd2, attn2, row_off, srcl, h2);

  pool_kernel<<<N_NODES, 128, 0, stream>>>(h2, gid, hg, cntg);
  final_kernel<<<GG, 64, 0, stream>>>(hg, cntg, Wr1, br1, Wr2, br2, out);
}

// Round 3
// 302.011 us; speedup vs baseline: 2.1984x; 1.2938x over previous
//
#include <hip/hip_runtime.h>

#define N_NODES 10000
#define N_EDGES 320000
#define DIM_IN  256
#define DD      128
#define HH      4
#define HD      512
#define GG      64

// ---------------- CSR build ----------------
__global__ void hist_kernel(const int* __restrict__ dst, int* __restrict__ cnt) {
  int e = blockIdx.x * 256 + threadIdx.x;
  atomicAdd(&cnt[dst[e]], 1);
}

__global__ void scan_kernel(const int* __restrict__ cnt, int* __restrict__ row_off) {
  __shared__ int part[1024];
  int t = threadIdx.x;
  int base = t * 10;
  int s = 0;
#pragma unroll
  for (int i = 0; i < 10; i++) { int idx = base + i; if (idx < N_NODES) s += cnt[idx]; }
  part[t] = s;
  __syncthreads();
  for (int off = 1; off < 1024; off <<= 1) {
    int v = (t >= off) ? part[t - off] : 0;
    __syncthreads();
    part[t] += v;
    __syncthreads();
  }
  int run = part[t] - s;
  for (int i = 0; i < 10; i++) {
    int idx = base + i;
    if (idx < N_NODES) { row_off[idx] = run; run += cnt[idx]; }
  }
  if (t == 1023) row_off[N_NODES] = part[1023];
}

__global__ void scatter_kernel(const int* __restrict__ src, const int* __restrict__ dst,
                               const int* __restrict__ row_off,
                               int* __restrict__ fill, int* __restrict__ srcl) {
  int e = blockIdx.x * 256 + threadIdx.x;
  int d = dst[e];
  int pos = row_off[d] + atomicAdd(&fill[d], 1);
  srcl[pos] = src[e];
}

// ---------------- dual GEMM: C1 = A@B1+bias1, C2 = A@B2+bias2 ----------------
// A-tile stored k-major (transposed) in LDS so the A fragment is a b128 read.
template <int K, int NCOL, int BM>
__global__ __launch_bounds__(256) void dual_gemm(
    const float* __restrict__ A,
    const float* __restrict__ B1, const float* __restrict__ bias1,
    const float* __restrict__ B2, const float* __restrict__ bias2,
    float* __restrict__ C1, float* __restrict__ C2, int M) {
  constexpr int MR = BM / 16;            // rows per thread (4 or 2)
  constexpr int TPR = 16 / MR;           // threads per A row-slice
  __shared__ float At[16][BM + 4];
  __shared__ float Bs[16][68];
  __shared__ float Bd[16][68];
  int t = threadIdx.x;
  int col0 = blockIdx.x * 64;
  int row0 = blockIdx.y * BM;
  int ar = t / TPR;
  int ac = (t % TPR) * MR;
  int bk = t >> 4, bc = (t & 15) * 4;
  int tx = t & 15, ty = t >> 4;
  float acc1[MR][4] = {}, acc2[MR][4] = {};
  for (int k0 = 0; k0 < K; k0 += 16) {
    float a_ld[MR] = {};
    if (row0 + ar < M) {
      if constexpr (MR == 4) {
        float4 av = *(const float4*)(A + (size_t)(row0 + ar) * K + k0 + ac);
        a_ld[0] = av.x; a_ld[1] = av.y; a_ld[2] = av.z; a_ld[3] = av.w;
      } else {
        float2 av = *(const float2*)(A + (size_t)(row0 + ar) * K + k0 + ac);
        a_ld[0] = av.x; a_ld[1] = av.y;
      }
    }
    float4 b1v = *(const float4*)(B1 + (size_t)(k0 + bk) * NCOL + col0 + bc);
    float4 b2v = *(const float4*)(B2 + (size_t)(k0 + bk) * NCOL + col0 + bc);
    __syncthreads();
#pragma unroll
    for (int q = 0; q < MR; q++) At[ac + q][ar] = a_ld[q];
    *(float4*)&Bs[bk][bc] = b1v;
    *(float4*)&Bd[bk][bc] = b2v;
    __syncthreads();
#pragma unroll
    for (int kk = 0; kk < 16; kk++) {
      float a[MR];
      if constexpr (MR == 4) {
        float4 a4 = *(const float4*)&At[kk][ty * 4];
        a[0] = a4.x; a[1] = a4.y; a[2] = a4.z; a[3] = a4.w;
      } else {
        float2 a2 = *(const float2*)&At[kk][ty * 2];
        a[0] = a2.x; a[1] = a2.y;
      }
      float4 br1 = *(const float4*)&Bs[kk][tx * 4];
      float4 br2 = *(const float4*)&Bd[kk][tx * 4];
      float b1r[4] = {br1.x, br1.y, br1.z, br1.w};
      float b2r[4] = {br2.x, br2.y, br2.z, br2.w};
#pragma unroll
      for (int i = 0; i < MR; i++)
#pragma unroll
        for (int j = 0; j < 4; j++) {
          acc1[i][j] = fmaf(a[i], b1r[j], acc1[i][j]);
          acc2[i][j] = fmaf(a[i], b2r[j], acc2[i][j]);
        }
    }
  }
#pragma unroll
  for (int i = 0; i < MR; i++) {
    int row = row0 + ty * MR + i;
    if (row < M) {
      float4 o1, o2;
      int cb = col0 + tx * 4;
      o1.x = acc1[i][0] + bias1[cb + 0]; o1.y = acc1[i][1] + bias1[cb + 1];
      o1.z = acc1[i][2] + bias1[cb + 2]; o1.w = acc1[i][3] + bias1[cb + 3];
      o2.x = acc2[i][0] + bias2[cb + 0]; o2.y = acc2[i][1] + bias2[cb + 1];
      o2.z = acc2[i][2] + bias2[cb + 2]; o2.w = acc2[i][3] + bias2[cb + 3];
      *(float4*)(C1 + (size_t)row * NCOL + cb) = o1;
      *(float4*)(C2 + (size_t)row * NCOL + cb) = o2;
    }
  }
}

// ---------------- layer 1 fused: scores + softmax (no max-shift) + aggregation --
// block = node, 4 waves; each wave processes edge PAIRS {2w,2w+1} step 8.
__global__ __launch_bounds__(256) void fused_gat1(
    const float* __restrict__ hs, const float* __restrict__ hd,
    const float* __restrict__ attn, const int* __restrict__ row_off,
    const int* __restrict__ srcl, float* __restrict__ out) {
  int v = blockIdx.x;
  int t = threadIdx.x;
  int w = t >> 6, lane = t & 63;
  int start = row_off[v];
  int deg = row_off[v + 1] - start;

  const float* ap = attn + lane * 8;
  const float* hp = hd + (size_t)v * HD + lane * 8;
  float4 a0 = *(const float4*)ap, a1 = *(const float4*)(ap + 4);
  float4 g0 = *(const float4*)hp, g1 = *(const float4*)(hp + 4);
  float areg[8] = {a0.x, a0.y, a0.z, a0.w, a1.x, a1.y, a1.z, a1.w};
  float hdreg[8] = {g0.x, g0.y, g0.z, g0.w, g1.x, g1.y, g1.z, g1.w};
  const float* hsl = hs + lane * 8;

  float ssum = 0.f;
  float acc[8] = {0.f, 0.f, 0.f, 0.f, 0.f, 0.f, 0.f, 0.f};

  int i = 2 * w;
  float4 p00 = {0,0,0,0}, p01 = {0,0,0,0}, p10 = {0,0,0,0}, p11 = {0,0,0,0};
  bool h0 = i < deg, h1 = i + 1 < deg;
  if (h0) { const float* p = hsl + (size_t)srcl[start + i] * HD; p00 = *(const float4*)p; p01 = *(const float4*)(p + 4); }
  if (h1) { const float* p = hsl + (size_t)srcl[start + i + 1] * HD; p10 = *(const float4*)p; p11 = *(const float4*)(p + 4); }
  while (h0) {
    float hv0[8] = {p00.x, p00.y, p00.z, p00.w, p01.x, p01.y, p01.z, p01.w};
    float hv1[8] = {p10.x, p10.y, p10.z, p10.w, p11.x, p11.y, p11.z, p11.w};
    bool h1c = h1;
    int inx = i + 8;
    h0 = inx < deg; h1 = inx + 1 < deg;
    if (h0) { const float* p = hsl + (size_t)srcl[start + inx] * HD; p00 = *(const float4*)p; p01 = *(const float4*)(p + 4); }
    if (h1) { const float* p = hsl + (size_t)srcl[start + inx + 1] * HD; p10 = *(const float4*)p; p11 = *(const float4*)(p + 4); }
    float part0 = 0.f, part1 = 0.f;
#pragma unroll
    for (int j = 0; j < 8; j++) {
      float u0 = hv0[j] + hdreg[j];
      u0 = fmaxf(u0, 0.2f * u0);
      part0 = fmaf(u0, areg[j], part0);
      float u1 = hv1[j] + hdreg[j];
      u1 = fmaxf(u1, 0.2f * u1);
      part1 = fmaf(u1, areg[j], part1);
    }
#pragma unroll
    for (int k = 1; k < 16; k <<= 1) {
      part0 += __shfl_xor(part0, k);
      part1 += __shfl_xor(part1, k);
    }
    float wg0 = __expf(part0);
    float wg1 = h1c ? __expf(part1) : 0.f;
    ssum += wg0 + wg1;
#pragma unroll
    for (int j = 0; j < 8; j++)
      acc[j] = fmaf(wg0, hv0[j], fmaf(wg1, hv1[j], acc[j]));
    i = inx;
  }

  __shared__ float accS[4][512];
  __shared__ float sS[4][4];
  *(float4*)&accS[w][lane * 8] = make_float4(acc[0], acc[1], acc[2], acc[3]);
  *(float4*)&accS[w][lane * 8 + 4] = make_float4(acc[4], acc[5], acc[6], acc[7]);
  if ((lane & 15) == 0) sS[w][lane >> 4] = ssum;
  __syncthreads();
#pragma unroll
  for (int rep = 0; rep < 2; rep++) {
    int slot = t + rep * 256;
    int h = slot >> 7;
    float denom = (sS[0][h] + sS[1][h]) + (sS[2][h] + sS[3][h]);
    float num = (accS[0][slot] + accS[1][slot]) + (accS[2][slot] + accS[3][slot]);
    out[(size_t)v * HD + slot] = denom > 0.f ? num / denom : 0.f;
  }
}

// ---------------- layer 2 fused (H=1, D=128): 16-lane group per edge ----------
__global__ __launch_bounds__(256) void fused_gat2(
    const float* __restrict__ hs, const float* __restrict__ hd,
    const float* __restrict__ attn, const int* __restrict__ row_off,
    const int* __restrict__ srcl, float* __restrict__ out) {
  int v = blockIdx.x;
  int t = threadIdx.x;
  int w = t >> 6, lane = t & 63, grp = lane >> 4, sl = lane & 15;
  int start = row_off[v];
  int deg = row_off[v + 1] - start;

  const float* ap = attn + sl * 8;
  const float* hp = hd + (size_t)v * DD + sl * 8;
  float4 a0 = *(const float4*)ap, a1 = *(const float4*)(ap + 4);
  float4 g0 = *(const float4*)hp, g1 = *(const float4*)(hp + 4);
  float areg[8] = {a0.x, a0.y, a0.z, a0.w, a1.x, a1.y, a1.z, a1.w};
  float hdreg[8] = {g0.x, g0.y, g0.z, g0.w, g1.x, g1.y, g1.z, g1.w};
  const float* hsl = hs + sl * 8;

  float ssum = 0.f;
  float acc[8] = {0.f, 0.f, 0.f, 0.f, 0.f, 0.f, 0.f, 0.f};

  int i = w * 4 + grp;
  float4 c0 = {0,0,0,0}, c1 = {0,0,0,0};
  bool has = i < deg;
  if (has) { const float* p = hsl + (size_t)srcl[start + i] * DD; c0 = *(const float4*)p; c1 = *(const float4*)(p + 4); }
  while (has) {
    float hv[8] = {c0.x, c0.y, c0.z, c0.w, c1.x, c1.y, c1.z, c1.w};
    int inx = i + 16;
    has = inx < deg;
    if (has) { const float* p = hsl + (size_t)srcl[start + inx] * DD; c0 = *(const float4*)p; c1 = *(const float4*)(p + 4); }
    float part = 0.f;
#pragma unroll
    for (int j = 0; j < 8; j++) {
      float u = hv[j] + hdreg[j];
      u = fmaxf(u, 0.2f * u);
      part = fmaf(u, areg[j], part);
    }
#pragma unroll
    for (int k = 1; k < 16; k <<= 1) part += __shfl_xor(part, k);
    float wg = __expf(part);
    ssum += wg;
#pragma unroll
    for (int j = 0; j < 8; j++) acc[j] = fmaf(wg, hv[j], acc[j]);
    i = inx;
  }

  __shared__ float accS[16][128];
  __shared__ float sS[16];
  int p = w * 4 + grp;
  *(float4*)&accS[p][sl * 8] = make_float4(acc[0], acc[1], acc[2], acc[3]);
  *(float4*)&accS[p][sl * 8 + 4] = make_float4(acc[4], acc[5], acc[6], acc[7]);
  if (sl == 0) sS[p] = ssum;
  __syncthreads();
  if (t < DD) {
    float denom = 0.f, num = 0.f;
#pragma unroll
    for (int q = 0; q < 16; q++) { denom += sS[q]; num += accS[q][t]; }
    out[(size_t)v * DD + t] = denom > 0.f ? num / denom : 0.f;
  }
}

// ---------------- pooling (binary search on sorted gid) + readout MLP ----------
__global__ __launch_bounds__(128) void final_kernel(
    const float* __restrict__ h2, const int* __restrict__ gid,
    const float* __restrict__ Wr1, const float* __restrict__ br1,
    const float* __restrict__ Wr2, const float* __restrict__ br2,
    float* __restrict__ out) {
  int g = blockIdx.x, t = threadIdx.x;
  int a, b;
  { int l = 0, h = N_NODES; while (l < h) { int m = (l + h) >> 1; if (gid[m] < g) l = m + 1; else h = m; } a = l; }
  { int l = a, h = N_NODES; while (l < h) { int m = (l + h) >> 1; if (gid[m] < g + 1) l = m + 1; else h = m; } b = l; }
  float s0 = 0.f, s1 = 0.f, s2 = 0.f, s3 = 0.f;
  int v = a;
  for (; v + 3 < b; v += 4) {
    s0 += h2[(size_t)(v + 0) * DD + t];
    s1 += h2[(size_t)(v + 1) * DD + t];
    s2 += h2[(size_t)(v + 2) * DD + t];
    s3 += h2[(size_t)(v + 3) * DD + t];
  }
  for (; v < b; v++) s0 += h2[(size_t)v * DD + t];
  __shared__ float hgn[128];
  float cnt = (float)(b - a);
  hgn[t] = ((s0 + s1) + (s2 + s3)) / fmaxf(cnt, 1.f);
  __syncthreads();
  if (t < 64) {
    float r = br1[t];
#pragma unroll 8
    for (int k = 0; k < 128; k++) r = fmaf(hgn[k], Wr1[k * 64 + t], r);
    r = fmaxf(r, 0.f);
    float p = r * Wr2[t];
#pragma unroll
    for (int k = 1; k < 64; k <<= 1) p += __shfl_xor(p, k);
    if (t == 0) out[g] = p + br2[0];
  }
}

extern "C" void kernel_launch(void* const* d_in, const int* in_sizes, int n_in,
                              void* d_out, int out_size, void* d_ws, size_t ws_size,
                              hipStream_t stream) {
  (void)in_sizes; (void)n_in; (void)out_size; (void)ws_size;
  const float* x     = (const float*)d_in[0];
  const float* W1s   = (const float*)d_in[1];
  const float* b1s   = (const float*)d_in[2];
  const float* W1d   = (const float*)d_in[3];
  const float* b1d   = (const float*)d_in[4];
  const float* attn1 = (const float*)d_in[5];
  const float* W2s   = (const float*)d_in[6];
  const float* b2s   = (const float*)d_in[7];
  const float* W2d   = (const float*)d_in[8];
  const float* b2d   = (const float*)d_in[9];
  const float* attn2 = (const float*)d_in[10];
  const float* Wr1   = (const float*)d_in[11];
  const float* br1   = (const float*)d_in[12];
  const float* Wr2   = (const float*)d_in[13];
  const float* br2   = (const float*)d_in[14];
  const int* src     = (const int*)d_in[15];
  const int* dst     = (const int*)d_in[16];
  const int* gid     = (const int*)d_in[17];
  float* out = (float*)d_out;

  char* ws = (char*)d_ws;
  float* hs1     = (float*)(ws + 0);          // N*512 f32 = 20,480,000 B
  float* hd1     = (float*)(ws + 20480000);   // N*512 f32
  float* h1      = (float*)(ws + 40960000);   // N*512 f32
  int*   srcl    = (int*)(ws + 61440000);     // E int = 1,280,000 B
  int*   row_off = (int*)(ws + 62720000);     // (N+1) int
  int*   cnt     = (int*)(ws + 62760448);     // N int
  int*   fill    = (int*)(ws + 62800896);     // N int
  // layer-2 reuse
  float* hs2 = hs1;
  float* hd2 = hd1;
  float* h2  = h1;   // gat2 reads hs1/hd1, writes h1 region (h1 no longer needed)

  hipMemsetAsync(cnt, 0, N_NODES * 4, stream);
  hipMemsetAsync(fill, 0, N_NODES * 4, stream);

  hist_kernel<<<N_EDGES / 256, 256, 0, stream>>>(dst, cnt);
  scan_kernel<<<1, 1024, 0, stream>>>(cnt, row_off);
  scatter_kernel<<<N_EDGES / 256, 256, 0, stream>>>(src, dst, row_off, fill, srcl);

  dual_gemm<DIM_IN, HD, 64><<<dim3(HD / 64, (N_NODES + 63) / 64), 256, 0, stream>>>(
      x, W1s, b1s, W1d, b1d, hs1, hd1, N_NODES);
  fused_gat1<<<N_NODES, 256, 0, stream>>>(hs1, hd1, attn1, row_off, srcl, h1);

  dual_gemm<HD, DD, 32><<<dim3(DD / 64, (N_NODES + 31) / 32), 256, 0, stream>>>(
      h1, W2s, b2s, W2d, b2d, hs2, hd2, N_NODES);
  fused_gat2<<<N_NODES, 256, 0, stream>>>(hs2, hd2, attn2, row_off, srcl, h2);

  final_kernel<<<GG, 128, 0, stream>>>(h2, gid, Wr1, br1, Wr2, br2, out);
}